// Round 8
// baseline (165.235 us; speedup 1.0000x reference)
//
#include <hip/hip_runtime.h>
#include <hip/hip_cooperative_groups.h>

namespace cg = cooperative_groups;

#define NN   8192
#define DIM  128

// ---- workspace layout (bytes) ----
#define OFF_H     0UL          // float H[8192][128]      4,194,304
#define OFF_ASRC  4194304UL    // float asrc[8192]           32,768
#define OFF_ADST  4227072UL    // float adst[8192]           32,768
#define OFF_MASK  4259840UL    // uint mask[256][8192]     8,388,608
#define WS_NEEDED 12648448UL

#define GC       256   // j-chunks (32 j's each -> one uint32 bitmask)
#define ROW_CAP  256   // max neighbors/row (mean 82; 19-sigma headroom)

// ---------------------------------------------------------------------------
// Cooperative mega-kernel; ALL work loops are grid-stride so any block count
// works. Phase 1: sparsify (2048 tiles) + gemm (256 tiles) + alpha (32 tiles),
// mutually independent, overlap inside one dispatch. grid.sync(). Phase 2:
// gather (1024 row-groups of 8 rows).
// ---------------------------------------------------------------------------
__global__ __launch_bounds__(256, 4) void k_mega(
    const float* __restrict__ x, const float* __restrict__ adj,
    const float* __restrict__ w, const float* __restrict__ att_s,
    const float* __restrict__ att_d, float* __restrict__ H,
    float* __restrict__ asrc, float* __restrict__ adst,
    unsigned int* __restrict__ mask, float* __restrict__ out)
{
    __shared__ union {
        struct { float xa[64][17]; float wb[16][68]; } g;        // 8704 B
        struct { float vs[128]; float vd[128]; } a;              // 1024 B
        struct { unsigned int mt[8][256];                        // 8192 B
                 int jl[4][257]; float wl[4][257]; } s;          // 16416 B
    } sm;

    const int tid  = threadIdx.x;
    const int b    = blockIdx.x;
    const int nblk = gridDim.x;

    // ================= Phase 1a: sparsify (grid-stride over 2048 tiles) ====
    for (int s = b; s < 2048; s += nblk) {
        const int ct = s & 7;
        const int g  = s >> 3;
        const int i0 = ct * 1024 + tid * 4;
        const float* base = adj + (size_t)(g * 32) * NN + i0;

        unsigned int m0 = 0, m1 = 0, m2 = 0, m3 = 0;
#pragma unroll 2
        for (int jj = 0; jj < 32; jj += 4) {
            const float* p = base + (size_t)jj * NN;
            float4 v0 = *reinterpret_cast<const float4*>(p);
            float4 v1 = *reinterpret_cast<const float4*>(p + NN);
            float4 v2 = *reinterpret_cast<const float4*>(p + 2 * NN);
            float4 v3 = *reinterpret_cast<const float4*>(p + 3 * NN);
#define PROC(v, dj)                                             \
            {                                                   \
                const unsigned int bb = 1u << (jj + (dj));      \
                if (v.x != 0.f) m0 |= bb;                       \
                if (v.y != 0.f) m1 |= bb;                       \
                if (v.z != 0.f) m2 |= bb;                       \
                if (v.w != 0.f) m3 |= bb;                       \
            }
            PROC(v0, 0) PROC(v1, 1) PROC(v2, 2) PROC(v3, 3)
#undef PROC
        }
        *reinterpret_cast<uint4*>(mask + (size_t)g * NN + i0) =
            make_uint4(m0, m1, m2, m3);
    }

    // ================= Phase 1b: gemm (grid-stride over 256 tiles) =========
    for (int t = b; t < 256; t += nblk) {
        const int i0g = (t >> 1) * 64;     // 64-row tile
        const int o0  = (t & 1) * 64;      // 64-col half
        const int tx  = tid & 15;
        const int ty  = tid >> 4;
        float acc[4][4];
#pragma unroll
        for (int i = 0; i < 4; ++i)
#pragma unroll
            for (int j = 0; j < 4; ++j) acc[i][j] = 0.f;

        for (int kt = 0; kt < 8; ++kt) {   // 8 k-tiles of 16
            __syncthreads();
            {   // stage x: 64 rows x 16 k
                const int r  = tid >> 2;
                const int kq = tid & 3;
                float4 v = *reinterpret_cast<const float4*>(
                    x + (size_t)(i0g + r) * DIM + kt * 16 + kq * 4);
                sm.g.xa[r][kq * 4 + 0] = v.x;
                sm.g.xa[r][kq * 4 + 1] = v.y;
                sm.g.xa[r][kq * 4 + 2] = v.z;
                sm.g.xa[r][kq * 4 + 3] = v.w;
            }
            {   // stage W^T: 16 k x 64 cols (transpose on write)
                const int o  = tid & 63;
                const int kq = tid >> 6;
                float4 v = *reinterpret_cast<const float4*>(
                    w + (size_t)(o0 + o) * DIM + kt * 16 + kq * 4);
                sm.g.wb[kq * 4 + 0][o] = v.x;
                sm.g.wb[kq * 4 + 1][o] = v.y;
                sm.g.wb[kq * 4 + 2][o] = v.z;
                sm.g.wb[kq * 4 + 3][o] = v.w;
            }
            __syncthreads();
#pragma unroll
            for (int kk = 0; kk < 16; ++kk) {
                float4 wv4 = *reinterpret_cast<const float4*>(&sm.g.wb[kk][tx * 4]);
#pragma unroll
                for (int i = 0; i < 4; ++i) {
                    const float xv = sm.g.xa[ty * 4 + i][kk];
                    acc[i][0] += xv * wv4.x;
                    acc[i][1] += xv * wv4.y;
                    acc[i][2] += xv * wv4.z;
                    acc[i][3] += xv * wv4.w;
                }
            }
        }
#pragma unroll
        for (int i = 0; i < 4; ++i)
            *reinterpret_cast<float4*>(
                H + (size_t)(i0g + ty * 4 + i) * DIM + o0 + tx * 4) =
                make_float4(acc[i][0], acc[i][1], acc[i][2], acc[i][3]);
    }

    // ================= Phase 1c: alpha (grid-stride over 32 tiles) =========
    for (int t = b; t < 32; t += nblk) {
        __syncthreads();   // protect LDS union transition (g -> a)
        {   // v = W^T att  (waves 0-1: src, 2-3: dst)
            const int is_d = tid >> 7;
            const int k    = tid & 127;
            const float* av = is_d ? att_d : att_s;
            float acc = 0.f;
            for (int o = 0; o < 128; ++o)
                acc += w[(size_t)o * 128 + k] * av[o];
            (is_d ? sm.a.vd : sm.a.vs)[k] = acc;
        }
        __syncthreads();
        const int r = t * 256 + tid;
        const float4* xr = reinterpret_cast<const float4*>(x + (size_t)r * DIM);
        float ss = 0.f, dd = 0.f;
#pragma unroll 8
        for (int q = 0; q < 32; ++q) {
            float4 xv = xr[q];
#pragma unroll
            for (int e = 0; e < 4; ++e) {
                const int k = q * 4 + e;
                const float xk = (&xv.x)[e];
                ss += xk * sm.a.vs[k];
                dd += xk * sm.a.vd[k];
            }
        }
        asrc[r] = ss;
        adst[r] = dd;
    }

    // ======================= grid-wide barrier =============================
    cg::this_grid().sync();

    // ================= Phase 2: gather (grid-stride over 1024 groups) ======
    const int lane = tid & 63;
    const int wv   = tid >> 6;

    for (int rg = b; rg < 1024; rg += nblk) {
        __syncthreads();   // all waves done with previous group's LDS
        const int i0 = rg * 8;

        // transposed mask tile: mt[ii][g]
#pragma unroll
        for (int p = 0; p < 2; ++p) {
            const int q   = p * 256 + tid;      // 0..511
            const int g   = q >> 1;
            const int ii4 = (q & 1) * 4;
            uint4 v = *reinterpret_cast<const uint4*>(mask + (size_t)g * NN + i0 + ii4);
            sm.s.mt[ii4 + 0][g] = v.x;
            sm.s.mt[ii4 + 1][g] = v.y;
            sm.s.mt[ii4 + 2][g] = v.z;
            sm.s.mt[ii4 + 3][g] = v.w;
        }
        __syncthreads();

        int* const   jl = sm.s.jl[wv];
        float* const wl = sm.s.wl[wv];

        for (int rr = 0; rr < 2; ++rr) {
            const int ii = wv * 2 + rr;
            const int i  = i0 + ii;

            // lane owns g = 4*lane..4*lane+3 (uint4 LDS read)
            uint4 mv = *reinterpret_cast<const uint4*>(&sm.s.mt[ii][4 * lane]);
            const int csum = __popc(mv.x) + __popc(mv.y) + __popc(mv.z) + __popc(mv.w);

            int incl = csum;
#pragma unroll
            for (int off = 1; off < 64; off <<= 1) {
                int tt = __shfl_up(incl, off);
                if (lane >= off) incl += tt;
            }
            const int cnt = min(__shfl(incl, 63), ROW_CAP);
            int off = incl - csum;

#define EXTRACT(mm, q)                                                  \
            {                                                           \
                unsigned int z = (mm);                                  \
                const int jb = (4 * lane + (q)) * 32;                   \
                while (z) {                                             \
                    const int bb = __builtin_ctz(z);                    \
                    z &= z - 1;                                         \
                    if (off < ROW_CAP) jl[off] = jb + bb;               \
                    ++off;                                              \
                }                                                       \
            }
            EXTRACT(mv.x, 0) EXTRACT(mv.y, 1) EXTRACT(mv.z, 2) EXTRACT(mv.w, 3)
#undef EXTRACT
            __builtin_amdgcn_wave_barrier();

            // weights + denominator
            const float adst_i = adst[i];
            float dsum = 0.f;
            for (int t = lane; t < cnt; t += 64) {
                const float cv = asrc[jl[t]] + adst_i;
                const float wgt = __expf(fmaxf(0.2f * cv, cv));
                wl[t] = wgt;
                dsum += wgt;
            }
#pragma unroll
            for (int mo = 1; mo < 64; mo <<= 1) dsum += __shfl_xor(dsum, mo);
            const float inv = 1.f / dsum;   // self-loops guarantee > 0

            // pad to even count (extra slot weight 0)
            if (lane == 0 && (cnt & 1)) { jl[cnt] = i; wl[cnt] = 0.f; }
            __builtin_amdgcn_wave_barrier();
            const int cnt2 = (cnt + 1) & ~1;

            // dual-neighbor gather: lanes 0-31 even k, 32-63 odd k
            const int half = lane >> 5;
            const int l32  = lane & 31;
            float4 acc = make_float4(0.f, 0.f, 0.f, 0.f);
            for (int k = 0; k < cnt2; k += 2) {
                const int   j  = jl[k + half];
                const float ww = wl[k + half];
                float4 h = *reinterpret_cast<const float4*>(H + (size_t)j * DIM + l32 * 4);
                acc.x += ww * h.x;
                acc.y += ww * h.y;
                acc.z += ww * h.z;
                acc.w += ww * h.w;
            }
            acc.x += __shfl_xor(acc.x, 32);
            acc.y += __shfl_xor(acc.y, 32);
            acc.z += __shfl_xor(acc.z, 32);
            acc.w += __shfl_xor(acc.w, 32);
            if (half == 0)
                *reinterpret_cast<float4*>(out + (size_t)i * DIM + l32 * 4) =
                    make_float4(acc.x * inv, acc.y * inv, acc.z * inv, acc.w * inv);
        }
    }
}

// ===========================================================================
// Fallback path (proven 3-kernel pipeline from R6), used if cooperative
// launch is unavailable. Identical math.
// ===========================================================================
__global__ __launch_bounds__(256, 8) void k_sparsify(
    const float* __restrict__ adj, unsigned int* __restrict__ mask)
{
    const int tid = threadIdx.x;
    const int bx  = blockIdx.x;
    const int col_tile = bx & 7;
    const int g  = bx >> 3;
    const int i0 = col_tile * 1024 + tid * 4;
    const float* base = adj + (size_t)(g * 32) * NN + i0;

    unsigned int m0 = 0, m1 = 0, m2 = 0, m3 = 0;
#pragma unroll 2
    for (int jj = 0; jj < 32; jj += 4) {
        const float* p = base + (size_t)jj * NN;
        float4 v0 = *reinterpret_cast<const float4*>(p);
        float4 v1 = *reinterpret_cast<const float4*>(p + NN);
        float4 v2 = *reinterpret_cast<const float4*>(p + 2 * NN);
        float4 v3 = *reinterpret_cast<const float4*>(p + 3 * NN);
#define PROC(v, dj)                                             \
        {                                                       \
            const unsigned int bb = 1u << (jj + (dj));          \
            if (v.x != 0.f) m0 |= bb;                           \
            if (v.y != 0.f) m1 |= bb;                           \
            if (v.z != 0.f) m2 |= bb;                           \
            if (v.w != 0.f) m3 |= bb;                           \
        }
        PROC(v0, 0) PROC(v1, 1) PROC(v2, 2) PROC(v3, 3)
#undef PROC
    }
    *reinterpret_cast<uint4*>(mask + (size_t)g * NN + i0) =
        make_uint4(m0, m1, m2, m3);
}

__global__ __launch_bounds__(256) void k_gemm_alpha(
    const float* __restrict__ x, const float* __restrict__ w,
    const float* __restrict__ att_s, const float* __restrict__ att_d,
    float* __restrict__ H, float* __restrict__ asrc, float* __restrict__ adst)
{
    __shared__ char smem[51712];
    const int tid = threadIdx.x;
    const int bx  = blockIdx.x;

    if (bx < 512) {
        const int i0   = (bx >> 1) * 32;
        const int half = bx & 1;
        float (*xs)[132] = reinterpret_cast<float(*)[132]>(smem);
        float (*wt)[68]  = reinterpret_cast<float(*)[68]>(smem + 32 * 132 * 4);

        for (int idx = tid; idx < 64 * 128; idx += 256) {
            int ol = idx >> 7, k = idx & 127;
            wt[k][ol] = w[(size_t)half * 8192 + idx];
        }
        for (int idx = tid; idx < 1024; idx += 256) {
            int r = idx >> 5, c = idx & 31;
            float4 v = reinterpret_cast<const float4*>(x + (size_t)(i0 + r) * DIM)[c];
            *reinterpret_cast<float4*>(&xs[r][c * 4]) = v;
        }
        __syncthreads();

        const int row = tid >> 3;
        const int obl = (tid & 7) * 8;
        float acc[8];
#pragma unroll
        for (int q = 0; q < 8; ++q) acc[q] = 0.f;
#pragma unroll 4
        for (int k0 = 0; k0 < 128; k0 += 4) {
            float4 xv = *reinterpret_cast<const float4*>(&xs[row][k0]);
#pragma unroll
            for (int kk = 0; kk < 4; ++kk) {
                float xk = (&xv.x)[kk];
#pragma unroll
                for (int q = 0; q < 2; ++q) {
                    float4 wv = *reinterpret_cast<const float4*>(&wt[k0 + kk][obl + q * 4]);
                    acc[q * 4 + 0] += xk * wv.x;
                    acc[q * 4 + 1] += xk * wv.y;
                    acc[q * 4 + 2] += xk * wv.z;
                    acc[q * 4 + 3] += xk * wv.w;
                }
            }
        }
        float* Hrow = H + (size_t)(i0 + row) * DIM + half * 64 + obl;
        reinterpret_cast<float4*>(Hrow)[0] = make_float4(acc[0], acc[1], acc[2], acc[3]);
        reinterpret_cast<float4*>(Hrow)[1] = make_float4(acc[4], acc[5], acc[6], acc[7]);
    } else {
        const int b = bx - 512;
        float* vs = reinterpret_cast<float*>(smem);
        float* vd = vs + 128;
        {
            const int is_d = tid >> 7;
            const int k    = tid & 127;
            const float* av = is_d ? att_d : att_s;
            float acc = 0.f;
            for (int o = 0; o < 128; ++o)
                acc += w[(size_t)o * 128 + k] * av[o];
            (is_d ? vd : vs)[k] = acc;
        }
        __syncthreads();
        const int r = b * 256 + tid;
        const float4* xr = reinterpret_cast<const float4*>(x + (size_t)r * DIM);
        float ss = 0.f, dd = 0.f;
#pragma unroll 8
        for (int q = 0; q < 32; ++q) {
            float4 xv = xr[q];
#pragma unroll
            for (int e = 0; e < 4; ++e) {
                const int k = q * 4 + e;
                const float xk = (&xv.x)[e];
                ss += xk * vs[k];
                dd += xk * vd[k];
            }
        }
        asrc[r] = ss;
        adst[r] = dd;
    }
}

__global__ __launch_bounds__(256, 4) void k_gather3(
    const unsigned int* __restrict__ mask, const float* __restrict__ H,
    const float* __restrict__ asrc, const float* __restrict__ adst,
    float* __restrict__ out)
{
    __shared__ unsigned int s_m[GC][17];
    __shared__ int   s_jl[4][ROW_CAP];
    __shared__ float s_w[4][ROW_CAP];

    const int tid  = threadIdx.x;
    const int lane = tid & 63;
    const int wv   = tid >> 6;
    const int i0   = blockIdx.x * 16;

#pragma unroll
    for (int p = 0; p < 4; ++p) {
        const int e  = p * 1024 + tid * 4;
        const int g  = e >> 4;
        const int ii = e & 15;
        uint4 v = *reinterpret_cast<const uint4*>(mask + (size_t)g * NN + i0 + ii);
        s_m[g][ii]     = v.x;
        s_m[g][ii + 1] = v.y;
        s_m[g][ii + 2] = v.z;
        s_m[g][ii + 3] = v.w;
    }
    __syncthreads();

    int* const jl = s_jl[wv];
    float* const wl = s_w[wv];

    for (int rr = 0; rr < 4; ++rr) {
        const int ii = wv * 4 + rr;
        const int i  = i0 + ii;

        unsigned int m0 = s_m[4 * lane + 0][ii];
        unsigned int m1 = s_m[4 * lane + 1][ii];
        unsigned int m2 = s_m[4 * lane + 2][ii];
        unsigned int m3 = s_m[4 * lane + 3][ii];
        const int csum = __popc(m0) + __popc(m1) + __popc(m2) + __popc(m3);

        int incl = csum;
#pragma unroll
        for (int off = 1; off < 64; off <<= 1) {
            int t = __shfl_up(incl, off);
            if (lane >= off) incl += t;
        }
        const int cnt = min(__shfl(incl, 63), ROW_CAP);
        int off = incl - csum;

#define EXTRACT(mm, q)                                                  \
        {                                                               \
            unsigned int z = (mm);                                      \
            const int jb = (4 * lane + (q)) * 32;                       \
            while (z) {                                                 \
                const int bb = __builtin_ctz(z);                        \
                z &= z - 1;                                             \
                if (off < ROW_CAP) jl[off] = jb + bb;                   \
                ++off;                                                  \
            }                                                           \
        }
        EXTRACT(m0, 0) EXTRACT(m1, 1) EXTRACT(m2, 2) EXTRACT(m3, 3)
#undef EXTRACT
        __builtin_amdgcn_wave_barrier();

        const float adst_i = adst[i];
        float dsum = 0.f;
        for (int t = lane; t < cnt; t += 64) {
            const float cv = asrc[jl[t]] + adst_i;
            const float wgt = __expf(fmaxf(0.2f * cv, cv));
            wl[t] = wgt;
            dsum += wgt;
        }
#pragma unroll
        for (int mo = 1; mo < 64; mo <<= 1) dsum += __shfl_xor(dsum, mo);
        const float inv = 1.f / dsum;

        float2 acc = make_float2(0.f, 0.f);
        for (int k = 0; k < cnt; ++k) {
            const int   j  = jl[k];
            const float ww = wl[k];
            float2 h = *reinterpret_cast<const float2*>(H + (size_t)j * DIM + lane * 2);
            acc.x += ww * h.x;
            acc.y += ww * h.y;
        }
        *reinterpret_cast<float2*>(out + (size_t)i * DIM + lane * 2) =
            make_float2(acc.x * inv, acc.y * inv);
    }
}

extern "C" void kernel_launch(void* const* d_in, const int* in_sizes, int n_in,
                              void* d_out, int out_size, void* d_ws, size_t ws_size,
                              hipStream_t stream)
{
    const float* x     = (const float*)d_in[0];
    const float* adj   = (const float*)d_in[1];
    const float* w     = (const float*)d_in[2];
    const float* att_s = (const float*)d_in[3];
    const float* att_d = (const float*)d_in[4];
    float* out = (float*)d_out;

    if (ws_size < WS_NEEDED) return;  // loud failure (output stays poisoned)

    char* ws = (char*)d_ws;
    float*        H    = (float*)(ws + OFF_H);
    float*        asrc = (float*)(ws + OFF_ASRC);
    float*        adst = (float*)(ws + OFF_ADST);
    unsigned int* mask = (unsigned int*)(ws + OFF_MASK);

    // ---- cooperative path: size the grid from the runtime's own occupancy
    int dev = 0;
    (void)hipGetDevice(&dev);
    int ncu = 0;
    (void)hipDeviceGetAttribute(&ncu, hipDeviceAttributeMultiprocessorCount, dev);
    int maxb = 0;
    hipError_t qerr = hipOccupancyMaxActiveBlocksPerMultiprocessor(&maxb, k_mega, 256, 0);

    long nblk = (long)maxb * (long)ncu;
    if (qerr == hipSuccess && nblk >= 64) {
        if (nblk > 1024) nblk = 1024;
        void* args[] = { (void*)&x, (void*)&adj, (void*)&w, (void*)&att_s,
                         (void*)&att_d, (void*)&H, (void*)&asrc, (void*)&adst,
                         (void*)&mask, (void*)&out };
        hipError_t lerr = hipLaunchCooperativeKernel(
            k_mega, dim3((unsigned)nblk), dim3(256), args, 0, stream);
        if (lerr == hipSuccess) return;
    }

    // ---- fallback: proven 3-kernel pipeline
    k_sparsify  <<<2048, 256, 0, stream>>>(adj, mask);
    k_gemm_alpha<<<544,  256, 0, stream>>>(x, w, att_s, att_d, H, asrc, adst);
    k_gather3   <<<512,  256, 0, stream>>>(mask, H, asrc, adst, out);
}

// Round 9
// 89.720 us; speedup vs baseline: 1.8417x; 1.8417x over previous
//
#include <hip/hip_runtime.h>

#define NN   8192
#define DIM  128

// ---- workspace layout (bytes) ----
#define OFF_HB    0UL          // ushort Hb[8192][128] (bf16)  2,097,152
#define OFF_ASRC  2097152UL    // float asrc[8192]                32,768
#define OFF_ADST  2129920UL    // float adst[8192]                32,768
#define OFF_MASK  2162688UL    // uint mask[256][8192]         8,388,608
#define WS_NEEDED 10551296UL

#define GC       256   // j-chunks (32 j's each -> one uint32 bitmask)
#define ROW_CAP  256   // max neighbors/row (mean 82; 19-sigma headroom)

__device__ __forceinline__ unsigned short f2bf(float f) {  // RNE
    unsigned int u = __builtin_bit_cast(unsigned int, f);
    u += 0x7fffu + ((u >> 16) & 1u);
    return (unsigned short)(u >> 16);
}
__device__ __forceinline__ float bf2f(unsigned short s) {
    return __builtin_bit_cast(float, (unsigned int)s << 16);
}

// ---------------------------------------------------------------------------
// K1 (block-role, small-LDS so ALL roles run 8 blocks/CU):
//   [0, 256)     gemm:  Hb = bf16(x W^T), 64x64 tiles, 8.7 KB LDS k-tiled
//   [256, 288)   alpha: asrc = x (W^T att_s), adst = x (W^T att_d)
//   [288, 2336)  sparsify: adj -> bitmasks (256 MB stream = the BW floor)
// gemm/alpha are dispatched FIRST so they overlap the sparsify stream.
// ---------------------------------------------------------------------------
__global__ __launch_bounds__(256, 8) void k_phase1(
    const float* __restrict__ x, const float* __restrict__ adj,
    const float* __restrict__ w, const float* __restrict__ att_s,
    const float* __restrict__ att_d, unsigned short* __restrict__ Hb,
    float* __restrict__ asrc, float* __restrict__ adst,
    unsigned int* __restrict__ mask)
{
    __shared__ union {
        struct { float xa[64][17]; float wb[16][68]; } g;   // 8704 B
        struct { float vs[128]; float vd[128]; } a;         // 1024 B
    } sm;

    const int tid = threadIdx.x;
    const int b   = blockIdx.x;

    if (b < 256) {
        // ---------------- gemm: one 64x64 tile (verified in R8) ------------
        const int i0g = (b >> 1) * 64;
        const int o0  = (b & 1) * 64;
        const int tx  = tid & 15;
        const int ty  = tid >> 4;
        float acc[4][4];
#pragma unroll
        for (int i = 0; i < 4; ++i)
#pragma unroll
            for (int j = 0; j < 4; ++j) acc[i][j] = 0.f;

        for (int kt = 0; kt < 8; ++kt) {   // 8 k-tiles of 16
            __syncthreads();
            {   // stage x: 64 rows x 16 k
                const int r  = tid >> 2;
                const int kq = tid & 3;
                float4 v = *reinterpret_cast<const float4*>(
                    x + (size_t)(i0g + r) * DIM + kt * 16 + kq * 4);
                sm.g.xa[r][kq * 4 + 0] = v.x;
                sm.g.xa[r][kq * 4 + 1] = v.y;
                sm.g.xa[r][kq * 4 + 2] = v.z;
                sm.g.xa[r][kq * 4 + 3] = v.w;
            }
            {   // stage W^T: 16 k x 64 cols (transpose on write)
                const int o  = tid & 63;
                const int kq = tid >> 6;
                float4 v = *reinterpret_cast<const float4*>(
                    w + (size_t)(o0 + o) * DIM + kt * 16 + kq * 4);
                sm.g.wb[kq * 4 + 0][o] = v.x;
                sm.g.wb[kq * 4 + 1][o] = v.y;
                sm.g.wb[kq * 4 + 2][o] = v.z;
                sm.g.wb[kq * 4 + 3][o] = v.w;
            }
            __syncthreads();
#pragma unroll
            for (int kk = 0; kk < 16; ++kk) {
                float4 wv4 = *reinterpret_cast<const float4*>(&sm.g.wb[kk][tx * 4]);
#pragma unroll
                for (int i = 0; i < 4; ++i) {
                    const float xv = sm.g.xa[ty * 4 + i][kk];
                    acc[i][0] += xv * wv4.x;
                    acc[i][1] += xv * wv4.y;
                    acc[i][2] += xv * wv4.z;
                    acc[i][3] += xv * wv4.w;
                }
            }
        }
#pragma unroll
        for (int i = 0; i < 4; ++i) {
            ushort4 h4;
            h4.x = f2bf(acc[i][0]);
            h4.y = f2bf(acc[i][1]);
            h4.z = f2bf(acc[i][2]);
            h4.w = f2bf(acc[i][3]);
            *reinterpret_cast<ushort4*>(
                Hb + (size_t)(i0g + ty * 4 + i) * DIM + o0 + tx * 4) = h4;
        }

    } else if (b < 288) {
        // ---------------- alpha (verified in R8) ---------------------------
        const int t = b - 256;             // 0..31
        {   // v = W^T att  (waves 0-1: src, 2-3: dst)
            const int is_d = tid >> 7;
            const int k    = tid & 127;
            const float* av = is_d ? att_d : att_s;
            float acc = 0.f;
            for (int o = 0; o < 128; ++o)
                acc += w[(size_t)o * 128 + k] * av[o];
            (is_d ? sm.a.vd : sm.a.vs)[k] = acc;
        }
        __syncthreads();
        const int r = t * 256 + tid;
        const float4* xr = reinterpret_cast<const float4*>(x + (size_t)r * DIM);
        float ss = 0.f, dd = 0.f;
#pragma unroll 8
        for (int q = 0; q < 32; ++q) {
            float4 xv = xr[q];
#pragma unroll
            for (int e = 0; e < 4; ++e) {
                const int k = q * 4 + e;
                const float xk = (&xv.x)[e];
                ss += xk * sm.a.vs[k];
                dd += xk * sm.a.vd[k];
            }
        }
        asrc[r] = ss;
        adst[r] = dd;

    } else {
        // ---------------- sparsify (verified R6 body) ----------------------
        const int s  = b - 288;            // 0..2047
        const int ct = s & 7;
        const int g  = s >> 3;
        const int i0 = ct * 1024 + tid * 4;
        const float* base = adj + (size_t)(g * 32) * NN + i0;

        unsigned int m0 = 0, m1 = 0, m2 = 0, m3 = 0;
#pragma unroll 2
        for (int jj = 0; jj < 32; jj += 4) {
            const float* p = base + (size_t)jj * NN;
            float4 v0 = *reinterpret_cast<const float4*>(p);
            float4 v1 = *reinterpret_cast<const float4*>(p + NN);
            float4 v2 = *reinterpret_cast<const float4*>(p + 2 * NN);
            float4 v3 = *reinterpret_cast<const float4*>(p + 3 * NN);
#define PROC(v, dj)                                             \
            {                                                   \
                const unsigned int bb = 1u << (jj + (dj));      \
                if (v.x != 0.f) m0 |= bb;                       \
                if (v.y != 0.f) m1 |= bb;                       \
                if (v.z != 0.f) m2 |= bb;                       \
                if (v.w != 0.f) m3 |= bb;                       \
            }
            PROC(v0, 0) PROC(v1, 1) PROC(v2, 2) PROC(v3, 3)
#undef PROC
        }
        *reinterpret_cast<uint4*>(mask + (size_t)g * NN + i0) =
            make_uint4(m0, m1, m2, m3);
    }
}

// ---------------------------------------------------------------------------
// K2 gather (verified R8 phase-2 body, H now bf16): 1024 blocks x 8 rows,
// XCD-chunked row map; transposed mask tile in LDS; per wave x 2 rows:
// popcount -> scan -> ctz extract -> exp weights -> butterfly denom ->
// dual-neighbor gather (lanes 0-31 even k, 32-63 odd k; ushort4 bf16 loads).
// ---------------------------------------------------------------------------
__global__ __launch_bounds__(256, 8) void k_gather(
    const unsigned int* __restrict__ mask, const unsigned short* __restrict__ Hb,
    const float* __restrict__ asrc, const float* __restrict__ adst,
    float* __restrict__ out)
{
    __shared__ unsigned int mt[8][256];          // 8192 B
    __shared__ int   s_jl[4][257];               // 4112 B
    __shared__ float s_wl[4][257];               // 4112 B

    const int tid  = threadIdx.x;
    const int b    = blockIdx.x;
    const int lane = tid & 63;
    const int wv   = tid >> 6;
    // XCD-chunked: blocks with the same (b&7) share consecutive row ranges
    const int i0 = (((b & 7) << 7) | (b >> 3)) * 8;

    // transposed mask tile: mt[ii][g]
#pragma unroll
    for (int p = 0; p < 2; ++p) {
        const int q   = p * 256 + tid;      // 0..511
        const int g   = q >> 1;
        const int ii4 = (q & 1) * 4;
        uint4 v = *reinterpret_cast<const uint4*>(mask + (size_t)g * NN + i0 + ii4);
        mt[ii4 + 0][g] = v.x;
        mt[ii4 + 1][g] = v.y;
        mt[ii4 + 2][g] = v.z;
        mt[ii4 + 3][g] = v.w;
    }
    __syncthreads();

    int* const   jl = s_jl[wv];
    float* const wl = s_wl[wv];

    for (int rr = 0; rr < 2; ++rr) {
        const int ii = wv * 2 + rr;
        const int i  = i0 + ii;

        uint4 mv = *reinterpret_cast<const uint4*>(&mt[ii][4 * lane]);
        const int csum = __popc(mv.x) + __popc(mv.y) + __popc(mv.z) + __popc(mv.w);

        int incl = csum;
#pragma unroll
        for (int off = 1; off < 64; off <<= 1) {
            int tt = __shfl_up(incl, off);
            if (lane >= off) incl += tt;
        }
        const int cnt = min(__shfl(incl, 63), ROW_CAP);
        int off = incl - csum;

#define EXTRACT(mm, q)                                                  \
        {                                                               \
            unsigned int z = (mm);                                      \
            const int jb = (4 * lane + (q)) * 32;                       \
            while (z) {                                                 \
                const int bb = __builtin_ctz(z);                        \
                z &= z - 1;                                             \
                if (off < ROW_CAP) jl[off] = jb + bb;                   \
                ++off;                                                  \
            }                                                           \
        }
        EXTRACT(mv.x, 0) EXTRACT(mv.y, 1) EXTRACT(mv.z, 2) EXTRACT(mv.w, 3)
#undef EXTRACT
        __builtin_amdgcn_wave_barrier();

        // weights + denominator
        const float adst_i = adst[i];
        float dsum = 0.f;
        for (int t = lane; t < cnt; t += 64) {
            const float cv = asrc[jl[t]] + adst_i;
            const float wgt = __expf(fmaxf(0.2f * cv, cv));
            wl[t] = wgt;
            dsum += wgt;
        }
#pragma unroll
        for (int mo = 1; mo < 64; mo <<= 1) dsum += __shfl_xor(dsum, mo);
        const float inv = 1.f / dsum;       // self-loops guarantee > 0

        // pad to even count (extra slot weight 0)
        if (lane == 0 && (cnt & 1)) { jl[cnt] = i; wl[cnt] = 0.f; }
        __builtin_amdgcn_wave_barrier();
        const int cnt2 = (cnt + 1) & ~1;

        // dual-neighbor gather: lanes 0-31 even k, 32-63 odd k (bf16 rows)
        const int half = lane >> 5;
        const int l32  = lane & 31;
        float4 acc = make_float4(0.f, 0.f, 0.f, 0.f);
        for (int k = 0; k < cnt2; k += 2) {
            const int   j  = jl[k + half];
            const float ww = wl[k + half];
            ushort4 h = *reinterpret_cast<const ushort4*>(Hb + (size_t)j * DIM + l32 * 4);
            acc.x += ww * bf2f(h.x);
            acc.y += ww * bf2f(h.y);
            acc.z += ww * bf2f(h.z);
            acc.w += ww * bf2f(h.w);
        }
        acc.x += __shfl_xor(acc.x, 32);
        acc.y += __shfl_xor(acc.y, 32);
        acc.z += __shfl_xor(acc.z, 32);
        acc.w += __shfl_xor(acc.w, 32);
        if (half == 0)
            *reinterpret_cast<float4*>(out + (size_t)i * DIM + l32 * 4) =
                make_float4(acc.x * inv, acc.y * inv, acc.z * inv, acc.w * inv);
    }
}

extern "C" void kernel_launch(void* const* d_in, const int* in_sizes, int n_in,
                              void* d_out, int out_size, void* d_ws, size_t ws_size,
                              hipStream_t stream)
{
    const float* x     = (const float*)d_in[0];
    const float* adj   = (const float*)d_in[1];
    const float* w     = (const float*)d_in[2];
    const float* att_s = (const float*)d_in[3];
    const float* att_d = (const float*)d_in[4];
    float* out = (float*)d_out;

    if (ws_size < WS_NEEDED) return;  // loud failure (output stays poisoned)

    char* ws = (char*)d_ws;
    unsigned short* Hb   = (unsigned short*)(ws + OFF_HB);
    float*          asrc = (float*)(ws + OFF_ASRC);
    float*          adst = (float*)(ws + OFF_ADST);
    unsigned int*   mask = (unsigned int*)(ws + OFF_MASK);

    k_phase1<<<2336, 256, 0, stream>>>(x, adj, w, att_s, att_d, Hb, asrc, adst, mask);
    k_gather<<<1024, 256, 0, stream>>>(mask, Hb, asrc, adst, out);
}